// Round 1
// baseline (139.806 us; speedup 1.0000x reference)
//
#include <hip/hip_runtime.h>
#include <math.h>

#define INO 128
#define INN 128
#define HID 64
#define NB  512
#define NN  2048

// pre[row][h] for row in [0,2560): rows [0,512) = xo@W1[:128] + b1,
// rows [512,2560) = xn@W1[128:]. One thread per (row,h).
__global__ __launch_bounds__(256) void pre_kernel(
    const float* __restrict__ xo, const float* __restrict__ xn,
    const float* __restrict__ W1, const float* __restrict__ b1,
    float* __restrict__ pre)
{
    int t = blockIdx.x * blockDim.x + threadIdx.x;
    int row = t >> 6;
    int h = t & 63;
    if (row >= NB + NN) return;
    const float* x;
    const float* w;
    float acc;
    if (row < NB) { x = xo + row * INO; w = W1;             acc = b1[h]; }
    else          { x = xn + (row - NB) * INN; w = W1 + INO * HID; acc = 0.f; }
#pragma unroll 8
    for (int k = 0; k < INO; ++k)
        acc = fmaf(x[k], w[k * HID + h], acc);
    pre[row * HID + h] = acc;
}

__device__ __forceinline__ float lrelu(float x) { return x > 0.f ? x : 0.2f * x; }

// One block per b-row: scores over n=0..2047, softmax, att@xn.
__global__ __launch_bounds__(256) void attn_kernel(
    const float* __restrict__ pre, const float* __restrict__ xn,
    const float* __restrict__ W2, float* __restrict__ out)
{
    const float* pre_o = pre;
    const float* pre_n = pre + NB * HID;
    const int b   = blockIdx.x;
    const int tid = threadIdx.x;

    __shared__ float s_pw[2 * HID];   // [0,64) = pre_o row, [64,128) = W2
    __shared__ float s_p[NN];         // softmax numerators
    __shared__ float s_red[8];        // per-wave max (0..3) and sum (4..7)
    __shared__ float s_part[256];     // column partial sums

    if (tid < HID)            s_pw[tid] = pre_o[b * HID + tid];
    else if (tid < 2 * HID)   s_pw[tid] = W2[tid - HID];
    __syncthreads();

    // ---- scores: each thread handles n = tid + 256*i, i in [0,8) ----
    float sc[8];
    float lmax = -1e30f;
#pragma unroll
    for (int i = 0; i < 8; ++i) {
        int n = tid + i * 256;
        const float4* pn = (const float4*)(pre_n + n * HID);
        float acc = 0.f;
#pragma unroll
        for (int j = 0; j < HID / 4; ++j) {
            float4 v = pn[j];
            float a0 = lrelu(s_pw[4 * j + 0] + v.x);
            float a1 = lrelu(s_pw[4 * j + 1] + v.y);
            float a2 = lrelu(s_pw[4 * j + 2] + v.z);
            float a3 = lrelu(s_pw[4 * j + 3] + v.w);
            acc = fmaf(a0, s_pw[HID + 4 * j + 0], acc);
            acc = fmaf(a1, s_pw[HID + 4 * j + 1], acc);
            acc = fmaf(a2, s_pw[HID + 4 * j + 2], acc);
            acc = fmaf(a3, s_pw[HID + 4 * j + 3], acc);
        }
        sc[i] = acc;
        lmax = fmaxf(lmax, acc);
    }

    // ---- block max ----
#pragma unroll
    for (int o = 32; o > 0; o >>= 1) lmax = fmaxf(lmax, __shfl_xor(lmax, o, 64));
    const int wid = tid >> 6;
    if ((tid & 63) == 0) s_red[wid] = lmax;
    __syncthreads();
    const float m = fmaxf(fmaxf(s_red[0], s_red[1]), fmaxf(s_red[2], s_red[3]));

    // ---- exp + block sum ----
    float lsum = 0.f;
#pragma unroll
    for (int i = 0; i < 8; ++i) {
        float p = __expf(sc[i] - m);
        s_p[tid + i * 256] = p;
        lsum += p;
    }
#pragma unroll
    for (int o = 32; o > 0; o >>= 1) lsum += __shfl_xor(lsum, o, 64);
    if ((tid & 63) == 0) s_red[4 + wid] = lsum;
    __syncthreads();
    const float denom = s_red[4] + s_red[5] + s_red[6] + s_red[7];

    // ---- out[b][c] = sum_n p[n] * xn[n][c] / denom ----
    const int c = tid & 127;
    const int half = tid >> 7;
    const float* xcol = xn + c;
    const int n0 = half * (NN / 2);
    float acc = 0.f;
#pragma unroll 8
    for (int n = n0; n < n0 + NN / 2; ++n)
        acc = fmaf(s_p[n], xcol[n * INN], acc);
    s_part[tid] = acc;
    __syncthreads();
    if (tid < 128)
        out[b * INN + tid] = (s_part[tid] + s_part[tid + 128]) / denom;
}

extern "C" void kernel_launch(void* const* d_in, const int* in_sizes, int n_in,
                              void* d_out, int out_size, void* d_ws, size_t ws_size,
                              hipStream_t stream) {
    const float* xo = (const float*)d_in[0];
    const float* xn = (const float*)d_in[1];
    const float* W1 = (const float*)d_in[2];
    const float* b1 = (const float*)d_in[3];
    const float* W2 = (const float*)d_in[4];
    // b2 (d_in[5]) is a uniform shift on scores -> cancels in softmax; skipped.
    float* out = (float*)d_out;
    float* pre = (float*)d_ws;  // (512+2048)*64 f32 = 640 KiB

    const int total = (NB + NN) * HID;
    pre_kernel<<<(total + 255) / 256, 256, 0, stream>>>(xo, xn, W1, b1, pre);
    attn_kernel<<<NB, 256, 0, stream>>>(pre, xn, W2, out);
}

// Round 3
// 111.576 us; speedup vs baseline: 1.2530x; 1.2530x over previous
//
#include <hip/hip_runtime.h>
#include <math.h>

#define INO 128
#define INN 128
#define HID 64
#define NB  512
#define NN  2048
#define TB  4            // b-rows per block
#define NCH 4            // n-chunks
#define NPC (NN / NCH)   // 512 n per chunk

// pre[row][h], rows [0,512)=xo@W1[:128]+b1, rows [512,2560)=xn@W1[128:].
__global__ __launch_bounds__(256) void pre_kernel(
    const float* __restrict__ xo, const float* __restrict__ xn,
    const float* __restrict__ W1, const float* __restrict__ b1,
    float* __restrict__ pre)
{
    int t = blockIdx.x * blockDim.x + threadIdx.x;
    int row = t >> 6;
    int h = t & 63;
    if (row >= NB + NN) return;
    const float* x;
    const float* w;
    float a0, a1 = 0.f, a2 = 0.f, a3 = 0.f;
    if (row < NB) { x = xo + row * INO;        w = W1;             a0 = b1[h]; }
    else          { x = xn + (row - NB) * INN; w = W1 + INO * HID; a0 = 0.f;  }
    const float4* x4 = (const float4*)x;
#pragma unroll
    for (int k4 = 0; k4 < INO / 4; ++k4) {
        float4 xv = x4[k4];
        int kb = k4 * 4;
        a0 = fmaf(xv.x, w[(kb + 0) * HID + h], a0);
        a1 = fmaf(xv.y, w[(kb + 1) * HID + h], a1);
        a2 = fmaf(xv.z, w[(kb + 2) * HID + h], a2);
        a3 = fmaf(xv.w, w[(kb + 3) * HID + h], a3);
    }
    pre[row * HID + h] = (a0 + a1) + (a2 + a3);
}

// One block per (b-tile of 4) x (n-chunk of 512): scores, local softmax
// stats, and PV partials.
__global__ __launch_bounds__(256) void score_pv_kernel(
    const float* __restrict__ pre, const float* __restrict__ xn,
    const float* __restrict__ W2,
    float* __restrict__ smax, float* __restrict__ ssum,
    float* __restrict__ part)
{
    const int bt = blockIdx.x >> 2;     // 0..127
    const int ch = blockIdx.x & 3;      // 0..3
    const int b0 = bt * TB;
    const int n0 = ch * NPC;
    const int tid = threadIdx.x;
    const int lane = tid & 63, wid = tid >> 6;

    __shared__ float  s_po[TB][HID];
    __shared__ float  s_w2[HID];
    __shared__ float4 s_p4[NPC];            // p[n_local] for 4 b's
    __shared__ float  s_red[4][2 * TB];     // per-wave max / sum
    __shared__ float  s_gacc[4][TB][INN];   // per-wave PV partials

    const float* pre_n = pre + NB * HID;
    s_po[tid >> 6][tid & 63] = pre[(b0 + (tid >> 6)) * HID + (tid & 63)];
    if (tid < HID) s_w2[tid] = W2[tid];
    __syncthreads();

    // ---- scores: thread owns n_local = tid and tid+256, all 4 b's ----
    float acc[2][TB] = {{0.f, 0.f, 0.f, 0.f}, {0.f, 0.f, 0.f, 0.f}};
    const float4* pn0 = (const float4*)(pre_n + (n0 + tid) * HID);
    const float4* pn1 = (const float4*)(pre_n + (n0 + tid + 256) * HID);
#pragma unroll
    for (int j = 0; j < HID / 4; ++j) {
        float4 v0 = pn0[j];
        float4 v1 = pn1[j];
#pragma unroll
        for (int hh = 0; hh < 4; ++hh) {
            float w = s_w2[4 * j + hh];
            float e0 = (&v0.x)[hh];
            float e1 = (&v1.x)[hh];
#pragma unroll
            for (int b = 0; b < TB; ++b) {
                float po = s_po[b][4 * j + hh];
                float t0 = po + e0;
                float t1 = po + e1;
                t0 = t0 > 0.f ? t0 : 0.2f * t0;
                t1 = t1 > 0.f ? t1 : 0.2f * t1;
                acc[0][b] = fmaf(t0, w, acc[0][b]);
                acc[1][b] = fmaf(t1, w, acc[1][b]);
            }
        }
    }

    // ---- per-b chunk max ----
    float m[TB];
#pragma unroll
    for (int b = 0; b < TB; ++b) {
        float v = fmaxf(acc[0][b], acc[1][b]);
#pragma unroll
        for (int o = 32; o > 0; o >>= 1) v = fmaxf(v, __shfl_xor(v, o, 64));
        if (lane == 0) s_red[wid][b] = v;
    }
    __syncthreads();
#pragma unroll
    for (int b = 0; b < TB; ++b)
        m[b] = fmaxf(fmaxf(s_red[0][b], s_red[1][b]),
                     fmaxf(s_red[2][b], s_red[3][b]));

    // ---- exp + chunk sum ----
    float p0[TB], p1[TB];
#pragma unroll
    for (int b = 0; b < TB; ++b) {
        p0[b] = __expf(acc[0][b] - m[b]);
        p1[b] = __expf(acc[1][b] - m[b]);
        float s = p0[b] + p1[b];
#pragma unroll
        for (int o = 32; o > 0; o >>= 1) s += __shfl_xor(s, o, 64);
        if (lane == 0) s_red[wid][TB + b] = s;
    }
    s_p4[tid]       = make_float4(p0[0], p0[1], p0[2], p0[3]);
    s_p4[tid + 256] = make_float4(p1[0], p1[1], p1[2], p1[3]);
    __syncthreads();
    if (tid < TB) {
        float sm = s_red[0][TB + tid] + s_red[1][TB + tid] +
                   s_red[2][TB + tid] + s_red[3][TB + tid];
        smax[ch * NB + b0 + tid] = m[tid];
        ssum[ch * NB + b0 + tid] = sm;
    }

    // ---- PV partials: wave w owns 128 n's; lane owns 2 columns ----
    float pacc[TB][2] = {};
    const int c0 = lane * 2;
#pragma unroll 4
    for (int k = 0; k < NPC / 4; ++k) {
        int nl = wid * (NPC / 4) + k;
        float2 xv = *(const float2*)(xn + (n0 + nl) * INN + c0);
        float4 pv = s_p4[nl];
        pacc[0][0] = fmaf(pv.x, xv.x, pacc[0][0]);
        pacc[0][1] = fmaf(pv.x, xv.y, pacc[0][1]);
        pacc[1][0] = fmaf(pv.y, xv.x, pacc[1][0]);
        pacc[1][1] = fmaf(pv.y, xv.y, pacc[1][1]);
        pacc[2][0] = fmaf(pv.z, xv.x, pacc[2][0]);
        pacc[2][1] = fmaf(pv.z, xv.y, pacc[2][1]);
        pacc[3][0] = fmaf(pv.w, xv.x, pacc[3][0]);
        pacc[3][1] = fmaf(pv.w, xv.y, pacc[3][1]);
    }
#pragma unroll
    for (int b = 0; b < TB; ++b) {
        s_gacc[wid][b][c0]     = pacc[b][0];
        s_gacc[wid][b][c0 + 1] = pacc[b][1];
    }
    __syncthreads();
#pragma unroll
    for (int t = 0; t < 2; ++t) {
        int idx = tid * 2 + t;
        int b = idx >> 7, c = idx & 127;
        float s = s_gacc[0][b][c] + s_gacc[1][b][c] +
                  s_gacc[2][b][c] + s_gacc[3][b][c];
        part[(ch * NB + b0 + b) * INN + c] = s;
    }
}

// out[b][c] = sum_ch part[ch][b][c]*e^{m_ch-M} / sum_ch ssum[ch][b]*e^{m_ch-M}
__global__ __launch_bounds__(256) void combine_kernel(
    const float* __restrict__ smax, const float* __restrict__ ssum,
    const float* __restrict__ part, float* __restrict__ out)
{
    int idx = blockIdx.x * 256 + threadIdx.x;   // 512*128
    int b = idx >> 7, c = idx & 127;
    float mv[NCH];
    float M = -1e30f;
#pragma unroll
    for (int ch = 0; ch < NCH; ++ch) {
        mv[ch] = smax[ch * NB + b];
        M = fmaxf(M, mv[ch]);
    }
    float den = 0.f, num = 0.f;
#pragma unroll
    for (int ch = 0; ch < NCH; ++ch) {
        float sc = __expf(mv[ch] - M);
        den = fmaf(ssum[ch * NB + b], sc, den);
        num = fmaf(part[(ch * NB + b) * INN + c], sc, num);
    }
    out[idx] = num / den;
}

extern "C" void kernel_launch(void* const* d_in, const int* in_sizes, int n_in,
                              void* d_out, int out_size, void* d_ws, size_t ws_size,
                              hipStream_t stream) {
    const float* xo = (const float*)d_in[0];
    const float* xn = (const float*)d_in[1];
    const float* W1 = (const float*)d_in[2];
    const float* b1 = (const float*)d_in[3];
    const float* W2 = (const float*)d_in[4];
    // b2 (d_in[5]) is a uniform shift on scores -> cancels in softmax.
    float* out = (float*)d_out;

    float* pre  = (float*)d_ws;                    // 2560*64 = 163840 f
    float* smax = pre + (NB + NN) * HID;           // NCH*512 = 2048 f
    float* ssum = smax + NCH * NB;                 // 2048 f
    float* part = ssum + NCH * NB;                 // NCH*512*128 = 262144 f
    // total ws use: ~1.68 MB

    const int total = (NB + NN) * HID;
    pre_kernel<<<(total + 255) / 256, 256, 0, stream>>>(xo, xn, W1, b1, pre);
    score_pv_kernel<<<(NB / TB) * NCH, 256, 0, stream>>>(pre, xn, W2, smax, ssum, part);
    combine_kernel<<<(NB * INN) / 256, 256, 0, stream>>>(smax, ssum, part, out);
}